// Round 1
// 2485.924 us; speedup vs baseline: 5.6306x; 5.6306x over previous
//
#include <hip/hip_runtime.h>

#define NSEQ 2048
#define BATCH 16
#define HDIM 256
#define PDIM 256
#define NLAYER 4
#define NCHUNK 64
#define CHLEN (NSEQ / NCHUNK)   // 32

__device__ __forceinline__ float gelu_tanh(float x) {
    float z = 0.7978845608028654f * (x + 0.044715f * x * x * x);
    return 0.5f * x * (1.f + tanhf(z));
}

// ---------------- LayerNorm: one wave per token, shuffle reduce ----------------
__global__ void ln_wave(const float* __restrict__ u, const float* __restrict__ sc,
                        const float* __restrict__ bs, float* __restrict__ out) {
    const int lane = threadIdx.x & 63;
    const int w = threadIdx.x >> 6;
    const size_t tok = (size_t)blockIdx.x * 4 + w;
    const size_t base = tok * 256 + (size_t)lane * 4;
    const float4 x = *(const float4*)&u[base];
    float s = x.x + x.y + x.z + x.w;
#pragma unroll
    for (int off = 32; off; off >>= 1) s += __shfl_xor(s, off, 64);
    const float mean = s * (1.f / 256.f);
    const float dx = x.x - mean, dy = x.y - mean, dz = x.z - mean, dw = x.w - mean;
    float v = dx * dx + dy * dy + dz * dz + dw * dw;
#pragma unroll
    for (int off = 32; off; off >>= 1) v += __shfl_xor(v, off, 64);
    const float rstd = rsqrtf(v * (1.f / 256.f) + 1e-5f);
    const float4 s4 = *(const float4*)&sc[lane * 4];
    const float4 b4 = *(const float4*)&bs[lane * 4];
    float4 o;
    o.x = dx * rstd * s4.x + b4.x;
    o.y = dy * rstd * s4.y + b4.y;
    o.z = dz * rstd * s4.z + b4.z;
    o.w = dw * rstd * s4.w + b4.w;
    *(float4*)&out[base] = o;
}

// ---------------- tiled fp32 GEMM: 64x64 tile, 4x4 microtile, 256 thr ----------------
// A: (M x lda) row-major; W0: (K x 256) row-major; KTOT=512 splits K into
// [W0 (k<256)] and [-W1n (k>=256)]  (for  y = Re@C_re - Im@C_im).
constexpr int EPI_DUP = 0, EPI_PLAIN = 1, EPI_GELU = 2;

template <int KTOT, int EPI>
__global__ __launch_bounds__(256) void gemm64(
    const float* __restrict__ A, int lda,
    const float* __restrict__ W0, const float* __restrict__ W1n,
    const float* __restrict__ bias,
    float* __restrict__ out0, float* __restrict__ out1, int ldo, int colofs) {
    __shared__ float As[32][68];   // [k][m], transposed, pad to 68 (16B-aligned rows)
    __shared__ float Ws[32][68];   // [k][n]
    const int m0 = blockIdx.x << 6, n0 = blockIdx.y << 6;
    const int tx = threadIdx.x & 15, ty = threadIdx.x >> 4;
    const int ar = threadIdx.x >> 3, ak = (threadIdx.x & 7) << 2;
    const int wk = threadIdx.x >> 4, wn = (threadIdx.x & 15) << 2;
    float acc[4][4] = {};
    for (int k0 = 0; k0 < KTOT; k0 += 32) {
        const float* Wsrc;
        float sgn = 1.f;
        if (KTOT == 512 && k0 >= 256) { Wsrc = W1n + (size_t)(k0 - 256) * 256; sgn = -1.f; }
        else                          { Wsrc = W0  + (size_t)k0 * 256; }
#pragma unroll
        for (int it = 0; it < 2; ++it) {   // A tile, transposed into LDS
            const int r = (it << 5) + ar;
            const float4 v = *(const float4*)&A[(size_t)(m0 + r) * lda + k0 + ak];
            As[ak + 0][r] = v.x; As[ak + 1][r] = v.y;
            As[ak + 2][r] = v.z; As[ak + 3][r] = v.w;
        }
#pragma unroll
        for (int it = 0; it < 2; ++it) {   // W tile, same orientation
            const int k = (it << 4) + wk;
            float4 w = *(const float4*)&Wsrc[(size_t)k * 256 + n0 + wn];
            if (KTOT == 512) { w.x *= sgn; w.y *= sgn; w.z *= sgn; w.w *= sgn; }
            *(float4*)&Ws[k][wn] = w;
        }
        __syncthreads();
#pragma unroll 8
        for (int k = 0; k < 32; ++k) {
            const float4 av = *(const float4*)&As[k][ty << 2];
            const float4 wv = *(const float4*)&Ws[k][tx << 2];
            const float aa[4] = {av.x, av.y, av.z, av.w};
            const float ww[4] = {wv.x, wv.y, wv.z, wv.w};
#pragma unroll
            for (int i = 0; i < 4; ++i)
#pragma unroll
                for (int j = 0; j < 4; ++j) acc[i][j] += aa[i] * ww[j];
        }
        __syncthreads();
    }
    const int nn = n0 + (tx << 2);
    float4 bv = {0.f, 0.f, 0.f, 0.f};
    if (bias) bv = *(const float4*)&bias[nn];
#pragma unroll
    for (int i = 0; i < 4; ++i) {
        const int row = m0 + (ty << 2) + i;
        float4 o;
        o.x = acc[i][0] + bv.x; o.y = acc[i][1] + bv.y;
        o.z = acc[i][2] + bv.z; o.w = acc[i][3] + bv.w;
        if constexpr (EPI == EPI_GELU) {
            o.x = gelu_tanh(o.x); o.y = gelu_tanh(o.y);
            o.z = gelu_tanh(o.z); o.w = gelu_tanh(o.w);
        }
        if constexpr (EPI == EPI_DUP) {
            *(float4*)&out0[(size_t)row * 256 + nn] = o;
            *(float4*)&out1[(size_t)row * 256 + nn] = o;
        } else {
            *(float4*)&out0[(size_t)row * ldo + colofs + nn] = o;
        }
    }
}

// ---------------- fused GLU GEMM: u += (g@W1+b1) * sigmoid(g@W2+b2) ----------------
__global__ __launch_bounds__(256) void gemm64_glu(
    const float* __restrict__ A,
    const float* __restrict__ W1, const float* __restrict__ W2,
    const float* __restrict__ b1, const float* __restrict__ b2,
    float* __restrict__ u) {
    __shared__ float As[32][68];
    __shared__ float W1s[32][68];
    __shared__ float W2s[32][68];
    const int m0 = blockIdx.x << 6, n0 = blockIdx.y << 6;
    const int tx = threadIdx.x & 15, ty = threadIdx.x >> 4;
    const int ar = threadIdx.x >> 3, ak = (threadIdx.x & 7) << 2;
    const int wk = threadIdx.x >> 4, wn = (threadIdx.x & 15) << 2;
    float acc1[4][4] = {}, acc2[4][4] = {};
    for (int k0 = 0; k0 < 256; k0 += 32) {
#pragma unroll
        for (int it = 0; it < 2; ++it) {
            const int r = (it << 5) + ar;
            const float4 v = *(const float4*)&A[(size_t)(m0 + r) * 256 + k0 + ak];
            As[ak + 0][r] = v.x; As[ak + 1][r] = v.y;
            As[ak + 2][r] = v.z; As[ak + 3][r] = v.w;
        }
#pragma unroll
        for (int it = 0; it < 2; ++it) {
            const int k = (it << 4) + wk;
            *(float4*)&W1s[k][wn] = *(const float4*)&W1[(size_t)(k0 + k) * 256 + n0 + wn];
            *(float4*)&W2s[k][wn] = *(const float4*)&W2[(size_t)(k0 + k) * 256 + n0 + wn];
        }
        __syncthreads();
#pragma unroll 4
        for (int k = 0; k < 32; ++k) {
            const float4 av = *(const float4*)&As[k][ty << 2];
            const float4 w1 = *(const float4*)&W1s[k][tx << 2];
            const float4 w2 = *(const float4*)&W2s[k][tx << 2];
            const float aa[4] = {av.x, av.y, av.z, av.w};
            const float p1[4] = {w1.x, w1.y, w1.z, w1.w};
            const float p2[4] = {w2.x, w2.y, w2.z, w2.w};
#pragma unroll
            for (int i = 0; i < 4; ++i)
#pragma unroll
                for (int j = 0; j < 4; ++j) {
                    acc1[i][j] += aa[i] * p1[j];
                    acc2[i][j] += aa[i] * p2[j];
                }
        }
        __syncthreads();
    }
    const int nn = n0 + (tx << 2);
    const float4 b1v = *(const float4*)&b1[nn];
    const float4 b2v = *(const float4*)&b2[nn];
    const float b1a[4] = {b1v.x, b1v.y, b1v.z, b1v.w};
    const float b2a[4] = {b2v.x, b2v.y, b2v.z, b2v.w};
#pragma unroll
    for (int i = 0; i < 4; ++i) {
        const int row = m0 + (ty << 2) + i;
        float4 uu = *(float4*)&u[(size_t)row * 256 + nn];
        float uo[4] = {uu.x, uu.y, uu.z, uu.w};
#pragma unroll
        for (int j = 0; j < 4; ++j) {
            const float t1 = acc1[i][j] + b1a[j];
            const float t2 = acc2[i][j] + b2a[j];
            uo[j] += t1 * (1.f / (1.f + expf(-t2)));
        }
        uu.x = uo[0]; uu.y = uo[1]; uu.z = uo[2]; uu.w = uo[3];
        *(float4*)&u[(size_t)row * 256 + nn] = uu;
    }
}

// ---------------- chunked complex scan, 3 passes ----------------
// pass 1: per-chunk reduce with zero init: A_c = prod a, E_c = local x_end
__global__ void scan_p1(const float* __restrict__ Bu, const float* __restrict__ dt,
                        const float* __restrict__ Lre, const float* __restrict__ Lim,
                        const float* __restrict__ ldl,
                        float* __restrict__ Ard, float* __restrict__ Erd) {
    const int c = blockIdx.x % NCHUNK, b = blockIdx.x / NCHUNK;
    const int p = threadIdx.x;
    const float lam_r = -expf(Lre[p]);
    const float lam_i = Lim[p];
    const float del = expf(ldl[p]);
    float Ar = 1.f, Ai = 0.f, xr = 0.f, xi = 0.f;
    const int n0 = c * CHLEN;
    for (int n = n0; n < n0 + CHLEN; ++n) {
        const float e = dt[b * NSEQ + n] * del;
        const float amag = expf(lam_r * e);
        float sn, cs;
        sincosf(lam_i * e, &sn, &cs);
        const float are = amag * cs, aim = amag * sn;
        const size_t tok = ((size_t)b * NSEQ + n) * 512;
        const float br = Bu[tok + p], bi = Bu[tok + 256 + p];
        const float nxr = are * xr - aim * xi + br;
        const float nxi = are * xi + aim * xr + bi;
        xr = nxr; xi = nxi;
        const float nAr = are * Ar - aim * Ai;
        const float nAi = are * Ai + aim * Ar;
        Ar = nAr; Ai = nAi;
    }
    const size_t o = ((size_t)b * NCHUNK + c) * 512;
    Ard[o + p] = Ar; Ard[o + 256 + p] = Ai;
    Erd[o + p] = xr; Erd[o + 256 + p] = xi;
}

// pass 2: tiny sequential scan over chunks -> chunk-start states S
__global__ void scan_p2(const float* __restrict__ Ard, const float* __restrict__ Erd,
                        const float* __restrict__ ire, const float* __restrict__ iim,
                        float* __restrict__ S) {
    const int b = blockIdx.x, p = threadIdx.x;
    float sr = ire[p], si = iim[p];
    for (int c = 0; c < NCHUNK; ++c) {
        const size_t o = ((size_t)b * NCHUNK + c) * 512;
        S[o + p] = sr; S[o + 256 + p] = si;
        const float ar = Ard[o + p], ai = Ard[o + 256 + p];
        const float er = Erd[o + p], ei = Erd[o + 256 + p];
        const float nr = ar * sr - ai * si + er;
        const float ni = ar * si + ai * sr + ei;
        sr = nr; si = ni;
    }
}

// pass 3: replay chunk with exact initial state; Xr may alias Bu (read-before-write per thread)
__global__ void scan_p3(const float* __restrict__ Bu, const float* __restrict__ dt,
                        const float* __restrict__ Lre, const float* __restrict__ Lim,
                        const float* __restrict__ ldl, const float* __restrict__ S,
                        float* __restrict__ Xr, float* __restrict__ Xl) {
    const int c = blockIdx.x % NCHUNK, b = blockIdx.x / NCHUNK;
    const int p = threadIdx.x;
    const float lam_r = -expf(Lre[p]);
    const float lam_i = Lim[p];
    const float del = expf(ldl[p]);
    const size_t o = ((size_t)b * NCHUNK + c) * 512;
    float xr = S[o + p], xi = S[o + 256 + p];
    const int n0 = c * CHLEN;
    for (int n = n0; n < n0 + CHLEN; ++n) {
        const float e = dt[b * NSEQ + n] * del;
        const float amag = expf(lam_r * e);
        float sn, cs;
        sincosf(lam_i * e, &sn, &cs);
        const float are = amag * cs, aim = amag * sn;
        const size_t tok = ((size_t)b * NSEQ + n) * 512;
        const float br = Bu[tok + p], bi = Bu[tok + 256 + p];
        const float lr = are * xr - aim * xi;   // x_left = a * x_prev
        const float li = are * xi + aim * xr;
        const float rr = lr + br;               // x_right = x_left + Bu
        const float ri = li + bi;
        Xl[tok + p] = lr; Xl[tok + 256 + p] = li;
        Xr[tok + p] = rr; Xr[tok + 256 + p] = ri;
        xr = rr; xi = ri;
    }
}

// ---------------- zero token 0 of each sequence ----------------
__global__ void zero_first(float* out) {
    out[(size_t)blockIdx.x * NSEQ * HDIM + threadIdx.x] = 0.f;
}

extern "C" void kernel_launch(void* const* d_in, const int* in_sizes, int n_in,
                              void* d_out, int out_size, void* d_ws, size_t ws_size,
                              hipStream_t stream) {
    const float* x_payload = (const float*)d_in[0];
    const float* dt        = (const float*)d_in[1];
    const float* embed_W   = (const float*)d_in[2];
    const float* embed_b   = (const float*)d_in[3];
    const float* ln_scale  = (const float*)d_in[4];
    const float* ln_bias   = (const float*)d_in[5];
    const float* Lambda_re = (const float*)d_in[6];
    const float* Lambda_im = (const float*)d_in[7];
    const float* log_delta = (const float*)d_in[8];
    const float* B_re      = (const float*)d_in[9];
    const float* B_im      = (const float*)d_in[10];
    const float* C_re      = (const float*)d_in[11];
    const float* C_im      = (const float*)d_in[12];
    const float* W1        = (const float*)d_in[13];
    const float* b1        = (const float*)d_in[14];
    const float* W2        = (const float*)d_in[15];
    const float* b2        = (const float*)d_in[16];
    const float* init_re   = (const float*)d_in[17];
    const float* init_im   = (const float*)d_in[18];

    auto footprint = [](int g) -> size_t {
        size_t T = (size_t)g * NSEQ;
        return T * 6144 + (size_t)g * NCHUNK * 512 * 4 * 3 + 65536;
    };
    int g = BATCH;
    while (g > 1 && footprint(g) > ws_size) g >>= 1;

    char* ws = (char*)d_ws;
    size_t off = 0;
    auto alloc = [&](size_t bytes) {
        void* p = ws + off;
        off = (off + bytes + 255) & ~(size_t)255;
        return p;
    };
    const size_t T = (size_t)g * NSEQ;
    const int Tg = (int)T;
    const int MT = Tg / 64;
    float* u_r  = (float*)alloc(T * 256 * 4);
    float* vbuf = (float*)alloc(T * 256 * 4);   // v_r; reused as gelu buffer
    float* BuB  = (float*)alloc(T * 512 * 4);   // Bu -> Xr (in place)
    float* Xl   = (float*)alloc(T * 512 * 4);
    float* Ard  = (float*)alloc((size_t)g * NCHUNK * 512 * 4);
    float* Erd  = (float*)alloc((size_t)g * NCHUNK * 512 * 4);
    float* Sbuf = (float*)alloc((size_t)g * NCHUNK * 512 * 4);
    float* Xr   = BuB;
    float* gbuf = vbuf;

    const dim3 gg(MT, 4);

    for (int b0 = 0; b0 < BATCH; b0 += g) {
        const float* xg  = x_payload + (size_t)b0 * NSEQ * HDIM;
        const float* dtg = dt + (size_t)b0 * NSEQ;
        float* u_l = (float*)d_out + (size_t)b0 * NSEQ * HDIM;  // left stream in d_out

        gemm64<256, EPI_DUP><<<gg, 256, 0, stream>>>(xg, 256, embed_W, nullptr, embed_b,
                                                     u_r, u_l, 256, 0);

        for (int l = 0; l < NLAYER; ++l) {
            const float* Brl = B_re + (size_t)l * 65536;
            const float* Bil = B_im + (size_t)l * 65536;
            const float* Crl = C_re + (size_t)l * 65536;
            const float* Cil = C_im + (size_t)l * 65536;
            const float* W1l = W1 + (size_t)l * 65536;
            const float* W2l = W2 + (size_t)l * 65536;
            const float* b1l = b1 + (size_t)l * 256;
            const float* b2l = b2 + (size_t)l * 256;
            const float* Lrl = Lambda_re + l * PDIM;
            const float* Lil = Lambda_im + l * PDIM;
            const float* ldll = log_delta + l * PDIM;
            const float* irl = init_re + l * PDIM;
            const float* iil = init_im + l * PDIM;

            // v_r = LN(right_u)
            ln_wave<<<Tg / 4, 256, 0, stream>>>(u_r, ln_scale + l * HDIM, ln_bias + l * HDIM, vbuf);
            // Bu = [v_r @ B_re | v_r @ B_im]
            gemm64<256, EPI_PLAIN><<<gg, 256, 0, stream>>>(vbuf, 256, Brl, nullptr, nullptr,
                                                           BuB, nullptr, 512, 0);
            gemm64<256, EPI_PLAIN><<<gg, 256, 0, stream>>>(vbuf, 256, Bil, nullptr, nullptr,
                                                           BuB, nullptr, 512, 256);
            // chunked scan -> Xr (in place over Bu), Xl
            scan_p1<<<g * NCHUNK, 256, 0, stream>>>(BuB, dtg, Lrl, Lil, ldll, Ard, Erd);
            scan_p2<<<g, 256, 0, stream>>>(Ard, Erd, irl, iil, Sbuf);
            scan_p3<<<g * NCHUNK, 256, 0, stream>>>(BuB, dtg, Lrl, Lil, ldll, Sbuf, Xr, Xl);

            if (l < NLAYER - 1) {   // right-stream update unused after last layer
                gemm64<512, EPI_GELU><<<gg, 256, 0, stream>>>(Xr, 512, Crl, Cil, nullptr,
                                                              gbuf, nullptr, 256, 0);
                gemm64_glu<<<gg, 256, 0, stream>>>(gbuf, W1l, W2l, b1l, b2l, u_r);
            }
            gemm64<512, EPI_GELU><<<gg, 256, 0, stream>>>(Xl, 512, Crl, Cil, nullptr,
                                                          gbuf, nullptr, 256, 0);
            gemm64_glu<<<gg, 256, 0, stream>>>(gbuf, W1l, W2l, b1l, b2l, u_l);
        }
        zero_first<<<g, 256, 0, stream>>>(u_l);
    }
}

// Round 2
// 1200.890 us; speedup vs baseline: 11.6558x; 2.0701x over previous
//
#include <hip/hip_runtime.h>

#define NSEQ 2048
#define BATCH 16
#define HDIM 256
#define PDIM 256
#define NLAYER 4
#define NCHUNK 64
#define CHLEN (NSEQ / NCHUNK)   // 32

typedef __attribute__((ext_vector_type(8))) short short8;
typedef __attribute__((ext_vector_type(4))) float f32x4;

__device__ __forceinline__ float gelu_tanh(float x) {
    float z = 0.7978845608028654f * (x + 0.044715f * x * x * x);
    return 0.5f * x * (1.f + tanhf(z));
}

// packed f32 -> 2x bf16 (RNE), low half = first operand
__device__ __forceinline__ unsigned cvt_pk_bf16(float a, float b) {
    unsigned r;
    asm("v_cvt_pk_bf16_f32 %0, %1, %2" : "=v"(r) : "v"(a), "v"(b));
    return r;
}
__device__ __forceinline__ float bflo(unsigned u) { return __uint_as_float(u << 16); }
__device__ __forceinline__ float bfhi(unsigned u) { return __uint_as_float(u & 0xffff0000u); }

// split float4 into hi-bf16 pair + residual-lo-bf16 pair
__device__ __forceinline__ void split4(const float4 v, uint2& h, uint2& l) {
    h.x = cvt_pk_bf16(v.x, v.y);
    h.y = cvt_pk_bf16(v.z, v.w);
    l.x = cvt_pk_bf16(v.x - bflo(h.x), v.y - bfhi(h.x));
    l.y = cvt_pk_bf16(v.z - bflo(h.y), v.w - bfhi(h.y));
}

// ---------------- weight prep: fp32 (K,256) -> split bf16 [k/8][ldn][8] ----------------
struct PrepJob { const float* src; short* dhi; short* dlo; int ldn; int colofs; float sgn; };
struct PrepArgs { PrepJob j[25]; };

__global__ void prep_w(PrepArgs a) {
    const PrepJob jb = a.j[blockIdx.y];
    __shared__ float t[8][256];
    const int kg = blockIdx.x, tid = threadIdx.x;
    const int r = tid >> 5, c = (tid & 31) * 8;
    const float* src = jb.src + (size_t)(kg * 8 + r) * 256 + c;
    *(float4*)&t[r][c]     = *(const float4*)src;
    *(float4*)&t[r][c + 4] = *(const float4*)(src + 4);
    __syncthreads();
    const int n = tid;
    float x[8];
#pragma unroll
    for (int q = 0; q < 8; ++q) x[q] = t[q][n] * jb.sgn;
    uint4 h, l;
    h.x = cvt_pk_bf16(x[0], x[1]); h.y = cvt_pk_bf16(x[2], x[3]);
    h.z = cvt_pk_bf16(x[4], x[5]); h.w = cvt_pk_bf16(x[6], x[7]);
    l.x = cvt_pk_bf16(x[0] - bflo(h.x), x[1] - bfhi(h.x));
    l.y = cvt_pk_bf16(x[2] - bflo(h.y), x[3] - bfhi(h.y));
    l.z = cvt_pk_bf16(x[4] - bflo(h.z), x[5] - bfhi(h.z));
    l.w = cvt_pk_bf16(x[6] - bflo(h.w), x[7] - bfhi(h.w));
    const size_t o = ((size_t)kg * jb.ldn + jb.colofs + n) * 8;
    *(uint4*)&jb.dhi[o] = h;
    *(uint4*)&jb.dlo[o] = l;
}

// ---------------- LayerNorm: one wave per token, shuffle reduce ----------------
__global__ void ln_wave(const float* __restrict__ u, const float* __restrict__ sc,
                        const float* __restrict__ bs, float* __restrict__ out) {
    const int lane = threadIdx.x & 63;
    const int w = threadIdx.x >> 6;
    const size_t tok = (size_t)blockIdx.x * 4 + w;
    const size_t base = tok * 256 + (size_t)lane * 4;
    const float4 x = *(const float4*)&u[base];
    float s = x.x + x.y + x.z + x.w;
#pragma unroll
    for (int off = 32; off; off >>= 1) s += __shfl_xor(s, off, 64);
    const float mean = s * (1.f / 256.f);
    const float dx = x.x - mean, dy = x.y - mean, dz = x.z - mean, dw = x.w - mean;
    float v = dx * dx + dy * dy + dz * dz + dw * dw;
#pragma unroll
    for (int off = 32; off; off >>= 1) v += __shfl_xor(v, off, 64);
    const float rstd = rsqrtf(v * (1.f / 256.f) + 1e-5f);
    const float4 s4 = *(const float4*)&sc[lane * 4];
    const float4 b4 = *(const float4*)&bs[lane * 4];
    float4 o;
    o.x = dx * rstd * s4.x + b4.x;
    o.y = dy * rstd * s4.y + b4.y;
    o.z = dz * rstd * s4.z + b4.z;
    o.w = dw * rstd * s4.w + b4.w;
    *(float4*)&out[base] = o;
}

// ---------------- MFMA GEMM: 128x256 block, 8 waves of 64x64, 3xbf16 split ----------------
constexpr int EPI_DUP = 0, EPI_PLAIN = 1, EPI_GELU = 2;

template <int KTOT, int EPI>
__global__ __launch_bounds__(512, 2) void gemm_mfma(
    const float* __restrict__ A, int lda,
    const short* __restrict__ Whi_g, const short* __restrict__ Wlo_g, int ldn,
    const float* __restrict__ bias,
    float* __restrict__ out0, float* __restrict__ out1, int ldo) {
    __shared__ short Ahi[4 * 128 * 8], Alo[4 * 128 * 8];     // 8KB each
    __shared__ short Whi[4 * 256 * 8], Wlo[4 * 256 * 8];     // 16KB each
    const int tid = threadIdx.x;
    const int m0 = blockIdx.x << 7, n0 = blockIdx.y << 8;
    const int wid = tid >> 6, l = tid & 63;
    const int wm = wid >> 2, wn = wid & 3;       // 2x4 wave grid of 64x64 tiles
    const int kq = l >> 4, lr = l & 15;
    const int sm = tid >> 2;                      // staging row
    const int klo = (tid & 3) * 4;                // staging k offset (fl4)
    const int kg0 = klo >> 3, sub0 = klo & 7;
    f32x4 acc[4][4];
#pragma unroll
    for (int i = 0; i < 4; ++i)
#pragma unroll
        for (int j = 0; j < 4; ++j) acc[i][j] = {0.f, 0.f, 0.f, 0.f};

    for (int k0 = 0; k0 < KTOT; k0 += 32) {
        __syncthreads();
        {   // A stage: rows m0..+127, k k0..+31, on-the-fly split
            const float* ap = A + (size_t)(m0 + sm) * lda + k0 + klo;
            const float4 v0 = *(const float4*)ap;
            const float4 v1 = *(const float4*)(ap + 16);
            uint2 h, lo;
            split4(v0, h, lo);
            const int i0 = (kg0 * 128 + sm) * 8 + sub0;
            *(uint2*)&Ahi[i0] = h; *(uint2*)&Alo[i0] = lo;
            split4(v1, h, lo);
            const int i1 = ((kg0 + 2) * 128 + sm) * 8 + sub0;
            *(uint2*)&Ahi[i1] = h; *(uint2*)&Alo[i1] = lo;
        }
        {   // W stage: straight copy of pre-split tiles (1024 uint4 per precision)
            const int krow = k0 >> 3;
#pragma unroll
            for (int t2 = 0; t2 < 2; ++t2) {
                const int u = tid + t2 * 512;
                const int kg = u >> 8, w = u & 255;
                const size_t so = ((size_t)(krow + kg) * ldn + n0 + w) * 8;
                const int di = (kg * 256 + w) * 8;
                *(uint4*)&Whi[di] = *(const uint4*)&Whi_g[so];
                *(uint4*)&Wlo[di] = *(const uint4*)&Wlo_g[so];
            }
        }
        __syncthreads();
        short8 ah[4], am[4];
#pragma unroll
        for (int i = 0; i < 4; ++i) {
            const int idx = (kq * 128 + wm * 64 + i * 16 + lr) * 8;
            ah[i] = *(const short8*)&Ahi[idx];
            am[i] = *(const short8*)&Alo[idx];
        }
#pragma unroll
        for (int j = 0; j < 4; ++j) {
            const int widx = (kq * 256 + wn * 64 + j * 16 + lr) * 8;
            const short8 wh = *(const short8*)&Whi[widx];
            const short8 wl = *(const short8*)&Wlo[widx];
#pragma unroll
            for (int i = 0; i < 4; ++i) {
                acc[i][j] = __builtin_amdgcn_mfma_f32_16x16x32_bf16(ah[i], wh, acc[i][j], 0, 0, 0);
                acc[i][j] = __builtin_amdgcn_mfma_f32_16x16x32_bf16(ah[i], wl, acc[i][j], 0, 0, 0);
                acc[i][j] = __builtin_amdgcn_mfma_f32_16x16x32_bf16(am[i], wh, acc[i][j], 0, 0, 0);
            }
        }
    }
    // epilogue: C/D layout col=lane&15, row=(lane>>4)*4+reg
#pragma unroll
    for (int j = 0; j < 4; ++j) {
        const int col = n0 + wn * 64 + j * 16 + lr;
        const float bv = bias ? bias[col] : 0.f;
#pragma unroll
        for (int i = 0; i < 4; ++i) {
#pragma unroll
            for (int r = 0; r < 4; ++r) {
                const int row = m0 + wm * 64 + i * 16 + kq * 4 + r;
                float o = acc[i][j][r] + bv;
                if constexpr (EPI == EPI_GELU) o = gelu_tanh(o);
                out0[(size_t)row * ldo + col] = o;
                if constexpr (EPI == EPI_DUP) out1[(size_t)row * ldo + col] = o;
            }
        }
    }
}

// ---------------- fused GLU MFMA GEMM: u += (g@W1+b1)*sigmoid(g@W2+b2) ----------------
__global__ __launch_bounds__(512, 2) void gemm_glu(
    const float* __restrict__ A,
    const short* __restrict__ W1h, const short* __restrict__ W1l,
    const short* __restrict__ W2h, const short* __restrict__ W2l,
    const float* __restrict__ b1, const float* __restrict__ b2,
    float* __restrict__ u) {
    __shared__ short Ahi[4 * 128 * 8], Alo[4 * 128 * 8];
    __shared__ short Wh1[4 * 128 * 8], Wl1[4 * 128 * 8];
    __shared__ short Wh2[4 * 128 * 8], Wl2[4 * 128 * 8];
    const int tid = threadIdx.x;
    const int m0 = blockIdx.x << 7, n0 = blockIdx.y << 7;
    const int wid = tid >> 6, l = tid & 63;
    const int wm = wid >> 2, wn = wid & 3;       // 2x4 wave grid of 64x32 tiles
    const int kq = l >> 4, lr = l & 15;
    const int sm = tid >> 2;
    const int klo = (tid & 3) * 4;
    const int kg0 = klo >> 3, sub0 = klo & 7;
    f32x4 acc1[4][2], acc2[4][2];
#pragma unroll
    for (int i = 0; i < 4; ++i)
#pragma unroll
        for (int j = 0; j < 2; ++j) {
            acc1[i][j] = {0.f, 0.f, 0.f, 0.f};
            acc2[i][j] = {0.f, 0.f, 0.f, 0.f};
        }

    for (int k0 = 0; k0 < 256; k0 += 32) {
        __syncthreads();
        {   // A stage
            const float* ap = A + (size_t)(m0 + sm) * 256 + k0 + klo;
            const float4 v0 = *(const float4*)ap;
            const float4 v1 = *(const float4*)(ap + 16);
            uint2 h, lo;
            split4(v0, h, lo);
            const int i0 = (kg0 * 128 + sm) * 8 + sub0;
            *(uint2*)&Ahi[i0] = h; *(uint2*)&Alo[i0] = lo;
            split4(v1, h, lo);
            const int i1 = ((kg0 + 2) * 128 + sm) * 8 + sub0;
            *(uint2*)&Ahi[i1] = h; *(uint2*)&Alo[i1] = lo;
        }
        {   // W1/W2 stage: 512 uint4 per array, one per thread
            const int kg = tid >> 7, w = tid & 127;
            const size_t so = ((size_t)((k0 >> 3) + kg) * 256 + n0 + w) * 8;
            const int di = (kg * 128 + w) * 8;
            *(uint4*)&Wh1[di] = *(const uint4*)&W1h[so];
            *(uint4*)&Wl1[di] = *(const uint4*)&W1l[so];
            *(uint4*)&Wh2[di] = *(const uint4*)&W2h[so];
            *(uint4*)&Wl2[di] = *(const uint4*)&W2l[so];
        }
        __syncthreads();
        short8 ah[4], am[4];
#pragma unroll
        for (int i = 0; i < 4; ++i) {
            const int idx = (kq * 128 + wm * 64 + i * 16 + lr) * 8;
            ah[i] = *(const short8*)&Ahi[idx];
            am[i] = *(const short8*)&Alo[idx];
        }
#pragma unroll
        for (int j = 0; j < 2; ++j) {
            const int widx = (kq * 128 + wn * 32 + j * 16 + lr) * 8;
            const short8 w1h = *(const short8*)&Wh1[widx];
            const short8 w1l = *(const short8*)&Wl1[widx];
            const short8 w2h = *(const short8*)&Wh2[widx];
            const short8 w2l = *(const short8*)&Wl2[widx];
#pragma unroll
            for (int i = 0; i < 4; ++i) {
                acc1[i][j] = __builtin_amdgcn_mfma_f32_16x16x32_bf16(ah[i], w1h, acc1[i][j], 0, 0, 0);
                acc1[i][j] = __builtin_amdgcn_mfma_f32_16x16x32_bf16(ah[i], w1l, acc1[i][j], 0, 0, 0);
                acc1[i][j] = __builtin_amdgcn_mfma_f32_16x16x32_bf16(am[i], w1h, acc1[i][j], 0, 0, 0);
                acc2[i][j] = __builtin_amdgcn_mfma_f32_16x16x32_bf16(ah[i], w2h, acc2[i][j], 0, 0, 0);
                acc2[i][j] = __builtin_amdgcn_mfma_f32_16x16x32_bf16(ah[i], w2l, acc2[i][j], 0, 0, 0);
                acc2[i][j] = __builtin_amdgcn_mfma_f32_16x16x32_bf16(am[i], w2h, acc2[i][j], 0, 0, 0);
            }
        }
    }
#pragma unroll
    for (int j = 0; j < 2; ++j) {
        const int col = n0 + wn * 32 + j * 16 + lr;
        const float c1 = b1[col], c2 = b2[col];
#pragma unroll
        for (int i = 0; i < 4; ++i) {
#pragma unroll
            for (int r = 0; r < 4; ++r) {
                const int row = m0 + wm * 64 + i * 16 + kq * 4 + r;
                const float t1 = acc1[i][j][r] + c1;
                const float t2 = acc2[i][j][r] + c2;
                const size_t o = (size_t)row * 256 + col;
                u[o] += t1 * (1.f / (1.f + expf(-t2)));
            }
        }
    }
}

// ---------------- chunked complex scan, 3 passes ----------------
__global__ void scan_p1(const float* __restrict__ Bu, const float* __restrict__ dt,
                        const float* __restrict__ Lre, const float* __restrict__ Lim,
                        const float* __restrict__ ldl,
                        float* __restrict__ Ard, float* __restrict__ Erd) {
    const int c = blockIdx.x % NCHUNK, b = blockIdx.x / NCHUNK;
    const int p = threadIdx.x;
    const float lam_r = -expf(Lre[p]);
    const float lam_i = Lim[p];
    const float del = expf(ldl[p]);
    float Ar = 1.f, Ai = 0.f, xr = 0.f, xi = 0.f;
    const int n0 = c * CHLEN;
    for (int n = n0; n < n0 + CHLEN; ++n) {
        const float e = dt[b * NSEQ + n] * del;
        const float amag = expf(lam_r * e);
        float sn, cs;
        sincosf(lam_i * e, &sn, &cs);
        const float are = amag * cs, aim = amag * sn;
        const size_t tok = ((size_t)b * NSEQ + n) * 512;
        const float br = Bu[tok + p], bi = Bu[tok + 256 + p];
        const float nxr = are * xr - aim * xi + br;
        const float nxi = are * xi + aim * xr + bi;
        xr = nxr; xi = nxi;
        const float nAr = are * Ar - aim * Ai;
        const float nAi = are * Ai + aim * Ar;
        Ar = nAr; Ai = nAi;
    }
    const size_t o = ((size_t)b * NCHUNK + c) * 512;
    Ard[o + p] = Ar; Ard[o + 256 + p] = Ai;
    Erd[o + p] = xr; Erd[o + 256 + p] = xi;
}

__global__ void scan_p2(const float* __restrict__ Ard, const float* __restrict__ Erd,
                        const float* __restrict__ ire, const float* __restrict__ iim,
                        float* __restrict__ S) {
    const int b = blockIdx.x, p = threadIdx.x;
    float sr = ire[p], si = iim[p];
    for (int c = 0; c < NCHUNK; ++c) {
        const size_t o = ((size_t)b * NCHUNK + c) * 512;
        S[o + p] = sr; S[o + 256 + p] = si;
        const float ar = Ard[o + p], ai = Ard[o + 256 + p];
        const float er = Erd[o + p], ei = Erd[o + 256 + p];
        const float nr = ar * sr - ai * si + er;
        const float ni = ar * si + ai * sr + ei;
        sr = nr; si = ni;
    }
}

__global__ void scan_p3(const float* __restrict__ Bu, const float* __restrict__ dt,
                        const float* __restrict__ Lre, const float* __restrict__ Lim,
                        const float* __restrict__ ldl, const float* __restrict__ S,
                        float* __restrict__ Xr, float* __restrict__ Xl, int writeXr) {
    const int c = blockIdx.x % NCHUNK, b = blockIdx.x / NCHUNK;
    const int p = threadIdx.x;
    const float lam_r = -expf(Lre[p]);
    const float lam_i = Lim[p];
    const float del = expf(ldl[p]);
    const size_t o = ((size_t)b * NCHUNK + c) * 512;
    float xr = S[o + p], xi = S[o + 256 + p];
    const int n0 = c * CHLEN;
    for (int n = n0; n < n0 + CHLEN; ++n) {
        const float e = dt[b * NSEQ + n] * del;
        const float amag = expf(lam_r * e);
        float sn, cs;
        sincosf(lam_i * e, &sn, &cs);
        const float are = amag * cs, aim = amag * sn;
        const size_t tok = ((size_t)b * NSEQ + n) * 512;
        const float br = Bu[tok + p], bi = Bu[tok + 256 + p];
        const float lr = are * xr - aim * xi;
        const float li = are * xi + aim * xr;
        const float rr = lr + br;
        const float ri = li + bi;
        Xl[tok + p] = lr; Xl[tok + 256 + p] = li;
        if (writeXr) { Xr[tok + p] = rr; Xr[tok + 256 + p] = ri; }
        xr = rr; xi = ri;
    }
}

__global__ void zero_first(float* out) {
    out[(size_t)blockIdx.x * NSEQ * HDIM + threadIdx.x] = 0.f;
}

extern "C" void kernel_launch(void* const* d_in, const int* in_sizes, int n_in,
                              void* d_out, int out_size, void* d_ws, size_t ws_size,
                              hipStream_t stream) {
    const float* x_payload = (const float*)d_in[0];
    const float* dt        = (const float*)d_in[1];
    const float* embed_W   = (const float*)d_in[2];
    const float* embed_b   = (const float*)d_in[3];
    const float* ln_scale  = (const float*)d_in[4];
    const float* ln_bias   = (const float*)d_in[5];
    const float* Lambda_re = (const float*)d_in[6];
    const float* Lambda_im = (const float*)d_in[7];
    const float* log_delta = (const float*)d_in[8];
    const float* B_re      = (const float*)d_in[9];
    const float* B_im      = (const float*)d_in[10];
    const float* C_re      = (const float*)d_in[11];
    const float* C_im      = (const float*)d_in[12];
    const float* W1        = (const float*)d_in[13];
    const float* b1        = (const float*)d_in[14];
    const float* W2        = (const float*)d_in[15];
    const float* b2        = (const float*)d_in[16];
    const float* init_re   = (const float*)d_in[17];
    const float* init_im   = (const float*)d_in[18];

    // weight prep buffers (shorts): emb 64K, per layer: WB 128K, WC 128K, W1 64K, W2 64K
    const size_t WB_SZ = 32 * 512 * 8, WC_SZ = 64 * 256 * 8, W_SZ = 32 * 256 * 8;
    const size_t wbytes = (W_SZ + NLAYER * (WB_SZ + WC_SZ + 2 * W_SZ)) * 2 * 2 + 4096;

    auto footprint = [&](int g) -> size_t {
        size_t T = (size_t)g * NSEQ;
        return T * 6144 + (size_t)g * NCHUNK * 512 * 4 * 3 + wbytes + 65536;
    };
    int g = BATCH;
    while (g > 1 && footprint(g) > ws_size) g >>= 1;

    char* ws = (char*)d_ws;
    size_t off = 0;
    auto alloc = [&](size_t bytes) {
        void* p = ws + off;
        off = (off + bytes + 255) & ~(size_t)255;
        return p;
    };
    const size_t T = (size_t)g * NSEQ;
    const int Tg = (int)T;
    const int MT = Tg / 128;
    float* u_r  = (float*)alloc(T * 256 * 4);
    float* vbuf = (float*)alloc(T * 256 * 4);
    float* BuB  = (float*)alloc(T * 512 * 4);
    float* Xl   = (float*)alloc(T * 512 * 4);
    float* Ard  = (float*)alloc((size_t)g * NCHUNK * 512 * 4);
    float* Erd  = (float*)alloc((size_t)g * NCHUNK * 512 * 4);
    float* Sbuf = (float*)alloc((size_t)g * NCHUNK * 512 * 4);
    short* embWh = (short*)alloc(W_SZ * 2);
    short* embWl = (short*)alloc(W_SZ * 2);
    short* WBh = (short*)alloc(NLAYER * WB_SZ * 2);
    short* WBl = (short*)alloc(NLAYER * WB_SZ * 2);
    short* WCh = (short*)alloc(NLAYER * WC_SZ * 2);
    short* WCl = (short*)alloc(NLAYER * WC_SZ * 2);
    short* W1h = (short*)alloc(NLAYER * W_SZ * 2);
    short* W1l = (short*)alloc(NLAYER * W_SZ * 2);
    short* W2h = (short*)alloc(NLAYER * W_SZ * 2);
    short* W2l = (short*)alloc(NLAYER * W_SZ * 2);
    float* Xr   = BuB;
    float* gbuf = vbuf;

    // ---- one-shot weight prep ----
    PrepArgs pa;
    int nj = 0;
    pa.j[nj++] = {embed_W, embWh, embWl, 256, 0, 1.f};
    for (int l = 0; l < NLAYER; ++l) {
        pa.j[nj++] = {B_re + (size_t)l * 65536, WBh + l * WB_SZ, WBl + l * WB_SZ, 512, 0, 1.f};
        pa.j[nj++] = {B_im + (size_t)l * 65536, WBh + l * WB_SZ, WBl + l * WB_SZ, 512, 256, 1.f};
        pa.j[nj++] = {C_re + (size_t)l * 65536, WCh + l * WC_SZ, WCl + l * WC_SZ, 256, 0, 1.f};
        pa.j[nj++] = {C_im + (size_t)l * 65536, WCh + l * WC_SZ + 32 * 256 * 8,
                      WCl + l * WC_SZ + 32 * 256 * 8, 256, 0, -1.f};
        pa.j[nj++] = {W1 + (size_t)l * 65536, W1h + l * W_SZ, W1l + l * W_SZ, 256, 0, 1.f};
        pa.j[nj++] = {W2 + (size_t)l * 65536, W2h + l * W_SZ, W2l + l * W_SZ, 256, 0, 1.f};
    }
    prep_w<<<dim3(32, nj), 256, 0, stream>>>(pa);

    for (int b0 = 0; b0 < BATCH; b0 += g) {
        const float* xg  = x_payload + (size_t)b0 * NSEQ * HDIM;
        const float* dtg = dt + (size_t)b0 * NSEQ;
        float* u_l = (float*)d_out + (size_t)b0 * NSEQ * HDIM;

        gemm_mfma<256, EPI_DUP><<<dim3(MT, 1), 512, 0, stream>>>(
            xg, 256, embWh, embWl, 256, embed_b, u_r, u_l, 256);

        for (int l = 0; l < NLAYER; ++l) {
            const float* b1l = b1 + (size_t)l * 256;
            const float* b2l = b2 + (size_t)l * 256;
            const float* Lrl = Lambda_re + l * PDIM;
            const float* Lil = Lambda_im + l * PDIM;
            const float* ldll = log_delta + l * PDIM;
            const float* irl = init_re + l * PDIM;
            const float* iil = init_im + l * PDIM;
            const short* wbh = WBh + l * WB_SZ, *wbl = WBl + l * WB_SZ;
            const short* wch = WCh + l * WC_SZ, *wcl = WCl + l * WC_SZ;
            const short* w1hl = W1h + l * W_SZ, *w1ll = W1l + l * W_SZ;
            const short* w2hl = W2h + l * W_SZ, *w2ll = W2l + l * W_SZ;

            ln_wave<<<Tg / 4, 256, 0, stream>>>(u_r, ln_scale + l * HDIM, ln_bias + l * HDIM, vbuf);
            // Bu = v_r @ [B_re | B_im]   (N=512)
            gemm_mfma<256, EPI_PLAIN><<<dim3(MT, 2), 512, 0, stream>>>(
                vbuf, 256, wbh, wbl, 512, nullptr, BuB, nullptr, 512);
            // chunked scan
            scan_p1<<<g * NCHUNK, 256, 0, stream>>>(BuB, dtg, Lrl, Lil, ldll, Ard, Erd);
            scan_p2<<<g, 256, 0, stream>>>(Ard, Erd, irl, iil, Sbuf);
            scan_p3<<<g * NCHUNK, 256, 0, stream>>>(BuB, dtg, Lrl, Lil, ldll, Sbuf, Xr, Xl,
                                                    l < NLAYER - 1 ? 1 : 0);
            if (l < NLAYER - 1) {
                gemm_mfma<512, EPI_GELU><<<dim3(MT, 1), 512, 0, stream>>>(
                    Xr, 512, wch, wcl, 256, nullptr, gbuf, nullptr, 256);
                gemm_glu<<<dim3(MT, 2), 512, 0, stream>>>(gbuf, w1hl, w1ll, w2hl, w2ll,
                                                          b1l, b2l, u_r);
            }
            gemm_mfma<512, EPI_GELU><<<dim3(MT, 1), 512, 0, stream>>>(
                Xl, 512, wch, wcl, 256, nullptr, gbuf, nullptr, 256);
            gemm_glu<<<dim3(MT, 2), 512, 0, stream>>>(gbuf, w1hl, w1ll, w2hl, w2ll,
                                                      b1l, b2l, u_l);
        }
        zero_first<<<g, 256, 0, stream>>>(u_l);
    }
}

// Round 3
// 1066.099 us; speedup vs baseline: 13.1295x; 1.1264x over previous
//
#include <hip/hip_runtime.h>

#define NSEQ 2048
#define BATCH 16
#define HDIM 256
#define PDIM 256
#define NLAYER 4
#define NCHUNK 64
#define CHLEN (NSEQ / NCHUNK)   // 32

typedef __attribute__((ext_vector_type(8))) short short8;
typedef __attribute__((ext_vector_type(4))) float f32x4;
typedef unsigned int u32;

__device__ __forceinline__ float gelu_tanh(float x) {
    float z = 0.7978845608028654f * (x + 0.044715f * x * x * x);
    return 0.5f * x * (1.f + tanhf(z));
}

// packed f32 -> 2x bf16 (RNE), low half = first operand
__device__ __forceinline__ unsigned cvt_pk_bf16(float a, float b) {
    unsigned r;
    asm("v_cvt_pk_bf16_f32 %0, %1, %2" : "=v"(r) : "v"(a), "v"(b));
    return r;
}
__device__ __forceinline__ float bflo(unsigned u) { return __uint_as_float(u << 16); }
__device__ __forceinline__ float bfhi(unsigned u) { return __uint_as_float(u & 0xffff0000u); }

__device__ __forceinline__ void split4(const float4 v, uint2& h, uint2& l) {
    h.x = cvt_pk_bf16(v.x, v.y);
    h.y = cvt_pk_bf16(v.z, v.w);
    l.x = cvt_pk_bf16(v.x - bflo(h.x), v.y - bfhi(h.x));
    l.y = cvt_pk_bf16(v.z - bflo(h.y), v.w - bfhi(h.y));
}

// 16B async global->LDS copy (lds dest must be wave-linear: base + lane*16)
typedef __attribute__((address_space(1))) const u32 gu32;
typedef __attribute__((address_space(3))) u32 lu32;
__device__ __forceinline__ void gl16(const void* g, void* l) {
    __builtin_amdgcn_global_load_lds((gu32*)g, (lu32*)l, 16, 0, 0);
}

// ---------------- weight prep: fp32 (K,256) -> split bf16 [k/8][ldn][8] ----------------
struct PrepJob { const float* src; short* dhi; short* dlo; int ldn; int colofs; float sgn; };
struct PrepArgs { PrepJob j[25]; };

__global__ void prep_w(PrepArgs a) {
    const PrepJob jb = a.j[blockIdx.y];
    __shared__ float t[8][256];
    const int kg = blockIdx.x, tid = threadIdx.x;
    const int r = tid >> 5, c = (tid & 31) * 8;
    const float* src = jb.src + (size_t)(kg * 8 + r) * 256 + c;
    *(float4*)&t[r][c]     = *(const float4*)src;
    *(float4*)&t[r][c + 4] = *(const float4*)(src + 4);
    __syncthreads();
    const int n = tid;
    float x[8];
#pragma unroll
    for (int q = 0; q < 8; ++q) x[q] = t[q][n] * jb.sgn;
    uint4 h, l;
    h.x = cvt_pk_bf16(x[0], x[1]); h.y = cvt_pk_bf16(x[2], x[3]);
    h.z = cvt_pk_bf16(x[4], x[5]); h.w = cvt_pk_bf16(x[6], x[7]);
    l.x = cvt_pk_bf16(x[0] - bflo(h.x), x[1] - bfhi(h.x));
    l.y = cvt_pk_bf16(x[2] - bflo(h.y), x[3] - bfhi(h.y));
    l.z = cvt_pk_bf16(x[4] - bflo(h.z), x[5] - bfhi(h.z));
    l.w = cvt_pk_bf16(x[6] - bflo(h.w), x[7] - bfhi(h.w));
    const size_t o = ((size_t)kg * jb.ldn + jb.colofs + n) * 8;
    *(uint4*)&jb.dhi[o] = h;
    *(uint4*)&jb.dlo[o] = l;
}

// ---------------- LayerNorm: one wave per token, shuffle reduce ----------------
__global__ void ln_wave(const float* __restrict__ u, const float* __restrict__ sc,
                        const float* __restrict__ bs, float* __restrict__ out) {
    const int lane = threadIdx.x & 63;
    const int w = threadIdx.x >> 6;
    const size_t tok = (size_t)blockIdx.x * 4 + w;
    const size_t base = tok * 256 + (size_t)lane * 4;
    const float4 x = *(const float4*)&u[base];
    float s = x.x + x.y + x.z + x.w;
#pragma unroll
    for (int off = 32; off; off >>= 1) s += __shfl_xor(s, off, 64);
    const float mean = s * (1.f / 256.f);
    const float dx = x.x - mean, dy = x.y - mean, dz = x.z - mean, dw = x.w - mean;
    float v = dx * dx + dy * dy + dz * dz + dw * dw;
#pragma unroll
    for (int off = 32; off; off >>= 1) v += __shfl_xor(v, off, 64);
    const float rstd = rsqrtf(v * (1.f / 256.f) + 1e-5f);
    const float4 s4 = *(const float4*)&sc[lane * 4];
    const float4 b4 = *(const float4*)&bs[lane * 4];
    float4 o;
    o.x = dx * rstd * s4.x + b4.x;
    o.y = dy * rstd * s4.y + b4.y;
    o.z = dz * rstd * s4.z + b4.z;
    o.w = dw * rstd * s4.w + b4.w;
    *(float4*)&out[base] = o;
}

// ---------------- MFMA GEMM: 128x128 block, 8 waves (64x32), double-buffered ----------------
constexpr int EPI_DUP = 0, EPI_PLAIN = 1, EPI_GELU = 2;

template <int KTOT, int EPI>
__global__ __launch_bounds__(512, 4) void gemm_mfma(
    const float* __restrict__ A, int lda,
    const short* __restrict__ Whi_g, const short* __restrict__ Wlo_g, int ldn,
    const float* __restrict__ bias,
    float* __restrict__ out0, float* __restrict__ out1, int ldo) {
    __shared__ short As[2][2][4][128][8];    // [buf][prec][kg][m][8]  32KB
    __shared__ short Wsd[2][2][4][128][8];   // [buf][prec][kg][n][8]  32KB
    const int tid = threadIdx.x;
    const int m0 = blockIdx.x << 7, n0 = blockIdx.y << 7;
    const int wid = tid >> 6, l = tid & 63;
    const int wm = wid >> 2, wn = wid & 3;        // 2x4 wave grid of 64x32 tiles
    const int kq = l >> 4, lr = l & 15;
    const int sm = tid >> 2;                       // A staging row
    const int klo = (tid & 3) * 4;
    const int kg0 = klo >> 3, sub0 = klo & 7;
    const int kgW = (tid >> 7) & 3, colw = tid & 127;   // W staging coords

    f32x4 acc[4][2];
#pragma unroll
    for (int i = 0; i < 4; ++i)
#pragma unroll
        for (int j = 0; j < 2; ++j) acc[i][j] = {0.f, 0.f, 0.f, 0.f};

    auto stageW = [&](int k0, int buf) {
        const size_t so = ((size_t)((k0 >> 3) + kgW) * ldn + n0 + colw) * 8;
        gl16(Whi_g + so, &Wsd[buf][0][kgW][colw][0]);
        gl16(Wlo_g + so, &Wsd[buf][1][kgW][colw][0]);
    };
    auto loadA = [&](int k0, float4& v0, float4& v1) {
        const float* ap = A + (size_t)(m0 + sm) * lda + k0 + klo;
        v0 = *(const float4*)ap;
        v1 = *(const float4*)(ap + 16);
    };
    auto writeA = [&](int buf, const float4 v0, const float4 v1) {
        uint2 h, lo;
        split4(v0, h, lo);
        *(uint2*)&As[buf][0][kg0][sm][sub0] = h;
        *(uint2*)&As[buf][1][kg0][sm][sub0] = lo;
        split4(v1, h, lo);
        *(uint2*)&As[buf][0][kg0 + 2][sm][sub0] = h;
        *(uint2*)&As[buf][1][kg0 + 2][sm][sub0] = lo;
    };

    // prologue: stage tile 0
    {
        float4 p0, p1;
        loadA(0, p0, p1);
        stageW(0, 0);
        writeA(0, p0, p1);
    }
    const int nt = KTOT / 32;
    for (int t = 0; t < nt; ++t) {
        const int cur = t & 1, nxt = cur ^ 1;
        __syncthreads();                       // tile t ready (drains vm+lgkm)
        const bool pre = (t + 1 < nt);
        float4 nv0, nv1;
        if (pre) {                             // issue next-tile loads early
            loadA((t + 1) * 32, nv0, nv1);
            stageW((t + 1) * 32, nxt);
        }
        short8 ah[4], am[4];
#pragma unroll
        for (int i = 0; i < 4; ++i) {
            const int row = wm * 64 + i * 16 + lr;
            ah[i] = *(const short8*)&As[cur][0][kq][row][0];
            am[i] = *(const short8*)&As[cur][1][kq][row][0];
        }
#pragma unroll
        for (int j = 0; j < 2; ++j) {
            const int col = wn * 32 + j * 16 + lr;
            const short8 wh = *(const short8*)&Wsd[cur][0][kq][col][0];
            const short8 wl = *(const short8*)&Wsd[cur][1][kq][col][0];
#pragma unroll
            for (int i = 0; i < 4; ++i) {
                acc[i][j] = __builtin_amdgcn_mfma_f32_16x16x32_bf16(ah[i], wh, acc[i][j], 0, 0, 0);
                acc[i][j] = __builtin_amdgcn_mfma_f32_16x16x32_bf16(ah[i], wl, acc[i][j], 0, 0, 0);
                acc[i][j] = __builtin_amdgcn_mfma_f32_16x16x32_bf16(am[i], wh, acc[i][j], 0, 0, 0);
            }
        }
        if (pre) writeA(nxt, nv0, nv1);        // split+write AFTER MFMA (latency hidden)
    }
    // epilogue: C/D layout col=lane&15, row=(lane>>4)*4+reg
#pragma unroll
    for (int j = 0; j < 2; ++j) {
        const int col = n0 + wn * 32 + j * 16 + lr;
        const float bv = bias ? bias[col] : 0.f;
#pragma unroll
        for (int i = 0; i < 4; ++i) {
#pragma unroll
            for (int r = 0; r < 4; ++r) {
                const int row = m0 + wm * 64 + i * 16 + kq * 4 + r;
                float o = acc[i][j][r] + bv;
                if constexpr (EPI == EPI_GELU) o = gelu_tanh(o);
                out0[(size_t)row * ldo + col] = o;
                if constexpr (EPI == EPI_DUP) out1[(size_t)row * ldo + col] = o;
            }
        }
    }
}

// ---------------- fused GLU MFMA GEMM: u += (g@W1+b1)*sigmoid(g@W2+b2) ----------------
// 128x64 block, 8 waves (64x16), double-buffered
__global__ __launch_bounds__(512, 4) void gemm_glu(
    const float* __restrict__ A,
    const short* __restrict__ W1h, const short* __restrict__ W1l,
    const short* __restrict__ W2h, const short* __restrict__ W2l,
    const float* __restrict__ b1, const float* __restrict__ b2,
    float* __restrict__ u) {
    __shared__ short As[2][2][4][128][8];   // 32KB
    __shared__ short Ws[2][4][4][64][8];    // [buf][w1h,w1l,w2h,w2l][kg][n][8] 32KB
    const int tid = threadIdx.x;
    const int m0 = blockIdx.x << 7, n0 = blockIdx.y << 6;
    const int wid = tid >> 6, l = tid & 63;
    const int wm = wid >> 2, wn = wid & 3;        // 2x4 wave grid of 64x16 tiles
    const int kq = l >> 4, lr = l & 15;
    const int sm = tid >> 2;
    const int klo = (tid & 3) * 4;
    const int kg0 = klo >> 3, sub0 = klo & 7;
    const int kgW = (tid >> 6) & 3, colw = tid & 63, selLo = (tid >> 8) & 1;

    f32x4 acc1[4], acc2[4];
#pragma unroll
    for (int i = 0; i < 4; ++i) {
        acc1[i] = {0.f, 0.f, 0.f, 0.f};
        acc2[i] = {0.f, 0.f, 0.f, 0.f};
    }

    auto stageW = [&](int k0, int buf) {
        const size_t so = ((size_t)((k0 >> 3) + kgW) * 256 + n0 + colw) * 8;
        const short* s1 = selLo ? W1l : W1h;
        const short* s2 = selLo ? W2l : W2h;
        gl16(s1 + so, &Ws[buf][selLo][kgW][colw][0]);
        gl16(s2 + so, &Ws[buf][2 + selLo][kgW][colw][0]);
    };
    auto loadA = [&](int k0, float4& v0, float4& v1) {
        const float* ap = A + (size_t)(m0 + sm) * 256 + k0 + klo;
        v0 = *(const float4*)ap;
        v1 = *(const float4*)(ap + 16);
    };
    auto writeA = [&](int buf, const float4 v0, const float4 v1) {
        uint2 h, lo;
        split4(v0, h, lo);
        *(uint2*)&As[buf][0][kg0][sm][sub0] = h;
        *(uint2*)&As[buf][1][kg0][sm][sub0] = lo;
        split4(v1, h, lo);
        *(uint2*)&As[buf][0][kg0 + 2][sm][sub0] = h;
        *(uint2*)&As[buf][1][kg0 + 2][sm][sub0] = lo;
    };

    {
        float4 p0, p1;
        loadA(0, p0, p1);
        stageW(0, 0);
        writeA(0, p0, p1);
    }
    for (int t = 0; t < 8; ++t) {
        const int cur = t & 1, nxt = cur ^ 1;
        __syncthreads();
        const bool pre = (t + 1 < 8);
        float4 nv0, nv1;
        if (pre) {
            loadA((t + 1) * 32, nv0, nv1);
            stageW((t + 1) * 32, nxt);
        }
        short8 ah[4], am[4];
#pragma unroll
        for (int i = 0; i < 4; ++i) {
            const int row = wm * 64 + i * 16 + lr;
            ah[i] = *(const short8*)&As[cur][0][kq][row][0];
            am[i] = *(const short8*)&As[cur][1][kq][row][0];
        }
        {
            const int col = wn * 16 + lr;
            const short8 w1h = *(const short8*)&Ws[cur][0][kq][col][0];
            const short8 w1l = *(const short8*)&Ws[cur][1][kq][col][0];
            const short8 w2h = *(const short8*)&Ws[cur][2][kq][col][0];
            const short8 w2l = *(const short8*)&Ws[cur][3][kq][col][0];
#pragma unroll
            for (int i = 0; i < 4; ++i) {
                acc1[i] = __builtin_amdgcn_mfma_f32_16x16x32_bf16(ah[i], w1h, acc1[i], 0, 0, 0);
                acc1[i] = __builtin_amdgcn_mfma_f32_16x16x32_bf16(ah[i], w1l, acc1[i], 0, 0, 0);
                acc1[i] = __builtin_amdgcn_mfma_f32_16x16x32_bf16(am[i], w1h, acc1[i], 0, 0, 0);
                acc2[i] = __builtin_amdgcn_mfma_f32_16x16x32_bf16(ah[i], w2h, acc2[i], 0, 0, 0);
                acc2[i] = __builtin_amdgcn_mfma_f32_16x16x32_bf16(ah[i], w2l, acc2[i], 0, 0, 0);
                acc2[i] = __builtin_amdgcn_mfma_f32_16x16x32_bf16(am[i], w2h, acc2[i], 0, 0, 0);
            }
        }
        if (pre) writeA(nxt, nv0, nv1);
    }
    {
        const int col = n0 + wn * 16 + lr;
        const float c1 = b1[col], c2 = b2[col];
#pragma unroll
        for (int i = 0; i < 4; ++i) {
#pragma unroll
            for (int r = 0; r < 4; ++r) {
                const int row = m0 + wm * 64 + i * 16 + kq * 4 + r;
                const float t1 = acc1[i][r] + c1;
                const float t2 = acc2[i][r] + c2;
                const size_t o = (size_t)row * 256 + col;
                u[o] += t1 * (1.f / (1.f + expf(-t2)));
            }
        }
    }
}

// ---------------- chunked complex scan, 3 passes ----------------
__global__ void scan_p1(const float* __restrict__ Bu, const float* __restrict__ dt,
                        const float* __restrict__ Lre, const float* __restrict__ Lim,
                        const float* __restrict__ ldl,
                        float* __restrict__ Ard, float* __restrict__ Erd) {
    const int c = blockIdx.x % NCHUNK, b = blockIdx.x / NCHUNK;
    const int p = threadIdx.x;
    const float lam_r = -expf(Lre[p]);
    const float lam_i = Lim[p];
    const float del = expf(ldl[p]);
    float Ar = 1.f, Ai = 0.f, xr = 0.f, xi = 0.f;
    const int n0 = c * CHLEN;
    for (int n = n0; n < n0 + CHLEN; ++n) {
        const float e = dt[b * NSEQ + n] * del;
        const float amag = expf(lam_r * e);
        float sn, cs;
        sincosf(lam_i * e, &sn, &cs);
        const float are = amag * cs, aim = amag * sn;
        const size_t tok = ((size_t)b * NSEQ + n) * 512;
        const float br = Bu[tok + p], bi = Bu[tok + 256 + p];
        const float nxr = are * xr - aim * xi + br;
        const float nxi = are * xi + aim * xr + bi;
        xr = nxr; xi = nxi;
        const float nAr = are * Ar - aim * Ai;
        const float nAi = are * Ai + aim * Ar;
        Ar = nAr; Ai = nAi;
    }
    const size_t o = ((size_t)b * NCHUNK + c) * 512;
    Ard[o + p] = Ar; Ard[o + 256 + p] = Ai;
    Erd[o + p] = xr; Erd[o + 256 + p] = xi;
}

__global__ void scan_p2(const float* __restrict__ Ard, const float* __restrict__ Erd,
                        const float* __restrict__ ire, const float* __restrict__ iim,
                        float* __restrict__ S) {
    const int b = blockIdx.x, p = threadIdx.x;
    float sr = ire[p], si = iim[p];
    for (int c = 0; c < NCHUNK; ++c) {
        const size_t o = ((size_t)b * NCHUNK + c) * 512;
        S[o + p] = sr; S[o + 256 + p] = si;
        const float ar = Ard[o + p], ai = Ard[o + 256 + p];
        const float er = Erd[o + p], ei = Erd[o + 256 + p];
        const float nr = ar * sr - ai * si + er;
        const float ni = ar * si + ai * sr + ei;
        sr = nr; si = ni;
    }
}

__global__ void scan_p3(const float* __restrict__ Bu, const float* __restrict__ dt,
                        const float* __restrict__ Lre, const float* __restrict__ Lim,
                        const float* __restrict__ ldl, const float* __restrict__ S,
                        float* __restrict__ Xr, float* __restrict__ Xl, int writeXr) {
    const int c = blockIdx.x % NCHUNK, b = blockIdx.x / NCHUNK;
    const int p = threadIdx.x;
    const float lam_r = -expf(Lre[p]);
    const float lam_i = Lim[p];
    const float del = expf(ldl[p]);
    const size_t o = ((size_t)b * NCHUNK + c) * 512;
    float xr = S[o + p], xi = S[o + 256 + p];
    const int n0 = c * CHLEN;
    for (int n = n0; n < n0 + CHLEN; ++n) {
        const float e = dt[b * NSEQ + n] * del;
        const float amag = expf(lam_r * e);
        float sn, cs;
        sincosf(lam_i * e, &sn, &cs);
        const float are = amag * cs, aim = amag * sn;
        const size_t tok = ((size_t)b * NSEQ + n) * 512;
        const float br = Bu[tok + p], bi = Bu[tok + 256 + p];
        const float lr = are * xr - aim * xi;
        const float li = are * xi + aim * xr;
        const float rr = lr + br;
        const float ri = li + bi;
        Xl[tok + p] = lr; Xl[tok + 256 + p] = li;
        if (writeXr) { Xr[tok + p] = rr; Xr[tok + 256 + p] = ri; }
        xr = rr; xi = ri;
    }
}

__global__ void zero_first(float* out) {
    out[(size_t)blockIdx.x * NSEQ * HDIM + threadIdx.x] = 0.f;
}

extern "C" void kernel_launch(void* const* d_in, const int* in_sizes, int n_in,
                              void* d_out, int out_size, void* d_ws, size_t ws_size,
                              hipStream_t stream) {
    const float* x_payload = (const float*)d_in[0];
    const float* dt        = (const float*)d_in[1];
    const float* embed_W   = (const float*)d_in[2];
    const float* embed_b   = (const float*)d_in[3];
    const float* ln_scale  = (const float*)d_in[4];
    const float* ln_bias   = (const float*)d_in[5];
    const float* Lambda_re = (const float*)d_in[6];
    const float* Lambda_im = (const float*)d_in[7];
    const float* log_delta = (const float*)d_in[8];
    const float* B_re      = (const float*)d_in[9];
    const float* B_im      = (const float*)d_in[10];
    const float* C_re      = (const float*)d_in[11];
    const float* C_im      = (const float*)d_in[12];
    const float* W1        = (const float*)d_in[13];
    const float* b1        = (const float*)d_in[14];
    const float* W2        = (const float*)d_in[15];
    const float* b2        = (const float*)d_in[16];
    const float* init_re   = (const float*)d_in[17];
    const float* init_im   = (const float*)d_in[18];

    const size_t WB_SZ = 32 * 512 * 8, WC_SZ = 64 * 256 * 8, W_SZ = 32 * 256 * 8;
    const size_t wbytes = (W_SZ + NLAYER * (WB_SZ + WC_SZ + 2 * W_SZ)) * 2 * 2 + 4096;

    auto footprint = [&](int g) -> size_t {
        size_t T = (size_t)g * NSEQ;
        return T * 6144 + (size_t)g * NCHUNK * 512 * 4 * 3 + wbytes + 65536;
    };
    int g = BATCH;
    while (g > 1 && footprint(g) > ws_size) g >>= 1;

    char* ws = (char*)d_ws;
    size_t off = 0;
    auto alloc = [&](size_t bytes) {
        void* p = ws + off;
        off = (off + bytes + 255) & ~(size_t)255;
        return p;
    };
    const size_t T = (size_t)g * NSEQ;
    const int Tg = (int)T;
    const int MT = Tg / 128;
    float* u_r  = (float*)alloc(T * 256 * 4);
    float* vbuf = (float*)alloc(T * 256 * 4);
    float* BuB  = (float*)alloc(T * 512 * 4);
    float* Xl   = (float*)alloc(T * 512 * 4);
    float* Ard  = (float*)alloc((size_t)g * NCHUNK * 512 * 4);
    float* Erd  = (float*)alloc((size_t)g * NCHUNK * 512 * 4);
    float* Sbuf = (float*)alloc((size_t)g * NCHUNK * 512 * 4);
    short* embWh = (short*)alloc(W_SZ * 2);
    short* embWl = (short*)alloc(W_SZ * 2);
    short* WBh = (short*)alloc(NLAYER * WB_SZ * 2);
    short* WBl = (short*)alloc(NLAYER * WB_SZ * 2);
    short* WCh = (short*)alloc(NLAYER * WC_SZ * 2);
    short* WCl = (short*)alloc(NLAYER * WC_SZ * 2);
    short* W1h = (short*)alloc(NLAYER * W_SZ * 2);
    short* W1l = (short*)alloc(NLAYER * W_SZ * 2);
    short* W2h = (short*)alloc(NLAYER * W_SZ * 2);
    short* W2l = (short*)alloc(NLAYER * W_SZ * 2);
    float* Xr   = BuB;
    float* gbuf = vbuf;

    // ---- one-shot weight prep ----
    PrepArgs pa;
    int nj = 0;
    pa.j[nj++] = {embed_W, embWh, embWl, 256, 0, 1.f};
    for (int l = 0; l < NLAYER; ++l) {
        pa.j[nj++] = {B_re + (size_t)l * 65536, WBh + l * WB_SZ, WBl + l * WB_SZ, 512, 0, 1.f};
        pa.j[nj++] = {B_im + (size_t)l * 65536, WBh + l * WB_SZ, WBl + l * WB_SZ, 512, 256, 1.f};
        pa.j[nj++] = {C_re + (size_t)l * 65536, WCh + l * WC_SZ, WCl + l * WC_SZ, 256, 0, 1.f};
        pa.j[nj++] = {C_im + (size_t)l * 65536, WCh + l * WC_SZ + 32 * 256 * 8,
                      WCl + l * WC_SZ + 32 * 256 * 8, 256, 0, -1.f};
        pa.j[nj++] = {W1 + (size_t)l * 65536, W1h + l * W_SZ, W1l + l * W_SZ, 256, 0, 1.f};
        pa.j[nj++] = {W2 + (size_t)l * 65536, W2h + l * W_SZ, W2l + l * W_SZ, 256, 0, 1.f};
    }
    prep_w<<<dim3(32, nj), 256, 0, stream>>>(pa);

    for (int b0 = 0; b0 < BATCH; b0 += g) {
        const float* xg  = x_payload + (size_t)b0 * NSEQ * HDIM;
        const float* dtg = dt + (size_t)b0 * NSEQ;
        float* u_l = (float*)d_out + (size_t)b0 * NSEQ * HDIM;

        gemm_mfma<256, EPI_DUP><<<dim3(MT, 2), 512, 0, stream>>>(
            xg, 256, embWh, embWl, 256, embed_b, u_r, u_l, 256);

        for (int l = 0; l < NLAYER; ++l) {
            const float* b1l = b1 + (size_t)l * 256;
            const float* b2l = b2 + (size_t)l * 256;
            const float* Lrl = Lambda_re + l * PDIM;
            const float* Lil = Lambda_im + l * PDIM;
            const float* ldll = log_delta + l * PDIM;
            const float* irl = init_re + l * PDIM;
            const float* iil = init_im + l * PDIM;
            const short* wbh = WBh + l * WB_SZ, *wbl = WBl + l * WB_SZ;
            const short* wch = WCh + l * WC_SZ, *wcl = WCl + l * WC_SZ;
            const short* w1hl = W1h + l * W_SZ, *w1ll = W1l + l * W_SZ;
            const short* w2hl = W2h + l * W_SZ, *w2ll = W2l + l * W_SZ;

            ln_wave<<<Tg / 4, 256, 0, stream>>>(u_r, ln_scale + l * HDIM, ln_bias + l * HDIM, vbuf);
            // Bu = v_r @ [B_re | B_im]   (N=512)
            gemm_mfma<256, EPI_PLAIN><<<dim3(MT, 4), 512, 0, stream>>>(
                vbuf, 256, wbh, wbl, 512, nullptr, BuB, nullptr, 512);
            // chunked scan
            scan_p1<<<g * NCHUNK, 256, 0, stream>>>(BuB, dtg, Lrl, Lil, ldll, Ard, Erd);
            scan_p2<<<g, 256, 0, stream>>>(Ard, Erd, irl, iil, Sbuf);
            scan_p3<<<g * NCHUNK, 256, 0, stream>>>(BuB, dtg, Lrl, Lil, ldll, Sbuf, Xr, Xl,
                                                    l < NLAYER - 1 ? 1 : 0);
            if (l < NLAYER - 1) {
                gemm_mfma<512, EPI_GELU><<<dim3(MT, 2), 512, 0, stream>>>(
                    Xr, 512, wch, wcl, 256, nullptr, gbuf, nullptr, 256);
                gemm_glu<<<dim3(MT, 4), 512, 0, stream>>>(gbuf, w1hl, w1ll, w2hl, w2ll,
                                                          b1l, b2l, u_r);
            }
            gemm_mfma<512, EPI_GELU><<<dim3(MT, 2), 512, 0, stream>>>(
                Xl, 512, wch, wcl, 256, nullptr, gbuf, nullptr, 256);
            gemm_glu<<<dim3(MT, 4), 512, 0, stream>>>(gbuf, w1hl, w1ll, w2hl, w2ll,
                                                      b1l, b2l, u_l);
        }
        zero_first<<<g, 256, 0, stream>>>(u_l);
    }
}